// Round 9
// baseline (251.122 us; speedup 1.0000x reference)
//
#include <hip/hip_runtime.h>
#include <math.h>

// GAU attention: LN -> silu(x@W^T+b) x4 -> P=relu^2(QK^T/sqrt(T)) -> AV=P@V -> (U*AV)@Wo^T+bo
// R20: extend the R19-verified occupancy lever (2-phase structure responds to TLP:
// P @4 blocks/CU improved while nothing else changed) to QKVU and G. OCC 3->4 on
// both (pure __launch_bounds__ change): LDS 32KB x 4 = 128 <= 160KB, VGPR 56 <= 128.
//  - QKVU: 1536 blocks at depth 4 -> 6/CU staggered, drain windows overlap less.
//  - G: 768 blocks = 0.75 rounds at 4/CU -> all resident from t=0, 16 waves/CU.
//  - P (2-phase 128x128 @4/CU), out (streaming), pre (slab pack): unchanged.

typedef __attribute__((ext_vector_type(8))) short short8;
typedef __attribute__((ext_vector_type(4))) short short4v;
typedef __attribute__((ext_vector_type(4))) float floatx4;

constexpr int HD = 768;
constexpr int TT = 2048;
constexpr long WElem = 589824;     // 768*768
constexpr long QKpb  = 1572864;    // 2048*768 shorts per batch
constexpr long Ppb   = 4194304;    // 2048*2048 shorts per batch

__device__ __forceinline__ short f2bf(float x) {
  unsigned u = __builtin_bit_cast(unsigned, x);
  u = u + 0x7fffu + ((u >> 16) & 1u);   // RNE
  return (short)(u >> 16);
}
__device__ __forceinline__ float bf2f(short s) {
  unsigned u = ((unsigned)(unsigned short)s) << 16;
  return __builtin_bit_cast(float, u);
}

// kf-major packed offset (in shorts) of element (i, c) of a row-major [R x C]
// matrix, KF = C/32. Layout: [strip = i>>6][kf = c>>5][frag mi = (i>>4)&3][512].
// Within-frag: lane = ((c&31)>>3)*16 + (i&15), elem = c&7.
__device__ __forceinline__ long pL(int i, int c, int KF) {
  return (((long)(i >> 6) * KF + (c >> 5)) * 4 + ((i >> 4) & 3)) * 512 +
         ((c & 31) >> 3) * 128 + (i & 15) * 8 + (c & 7);
}

typedef __attribute__((address_space(1))) void void_g;
typedef __attribute__((address_space(3))) void void_l;
__device__ __forceinline__ void gload16(const void* g, void* l) {
  __builtin_amdgcn_global_load_lds((const void_g*)g, (void_l*)l, 16, 0, 0);
}

// ---------------- preprocessing: 16-row slabs, whole-frag coalesced writes ---------
// blocks [0,512): LN slabs of x (16 rows each); [512,752): weight slabs; 752: bias.
__global__ __launch_bounds__(256) void pre_kernel(
    const float* __restrict__ x, const float* __restrict__ g,
    const float* __restrict__ b, short* __restrict__ out,
    const float* __restrict__ wu, const float* __restrict__ wq,
    const float* __restrict__ wk, const float* __restrict__ wv,
    const float* __restrict__ wo,
    const float* __restrict__ bu, const float* __restrict__ bq,
    const float* __restrict__ bk, const float* __restrict__ bv,
    short* __restrict__ Wb, float* __restrict__ bcat) {
  int t = threadIdx.x;
  int bid = blockIdx.x;
  if (bid == 752) {                      // bias concat
#pragma unroll
    for (int j = 0; j < 12; j++) {
      int i = j * 256 + t;
      int which = i / HD, off = i - which * HD;
      const float* src = which == 0 ? bu : which == 1 ? bq : which == 2 ? bk : bv;
      bcat[i] = src[off];
    }
    return;
  }
  bool isLN = bid < 512;
  const float* src; short* dst; int rowbase;
  if (isLN) {
    rowbase = bid * 16; src = x + (long)rowbase * HD; dst = out;
  } else {
    int wb = bid - 512, which = wb / 48, rg = wb - which * 48;
    rowbase = rg * 16;
    src = (which == 0 ? wu : which == 1 ? wq : which == 2 ? wk
         : which == 3 ? wv : wo) + (long)rowbase * HD;
    dst = Wb + (long)which * WElem;
  }
  int lane = t & 63, w = t >> 6;
  __shared__ float stats[32];
  if (isLN) {
    int r = t >> 4, q = t & 15;          // 16 lanes per row
    float s = 0.f, ss = 0.f;
#pragma unroll
    for (int j = 0; j < 12; j++) {
      floatx4 v = *(const floatx4*)&src[(long)r * HD + q * 4 + j * 64];
#pragma unroll
      for (int e = 0; e < 4; e++) { s += v[e]; ss += v[e] * v[e]; }
    }
#pragma unroll
    for (int m = 1; m < 16; m <<= 1) {
      s += __shfl_xor(s, m); ss += __shfl_xor(ss, m);
    }
    if (q == 0) {
      float mean = s * (1.0f / HD);
      float var = ss * (1.0f / HD) - mean * mean;
      stats[r * 2] = mean;
      stats[r * 2 + 1] = rsqrtf(var + 1e-5f);
    }
    __syncthreads();
  }
  int oct = lane >> 4, i15 = lane & 15;
  float mean = 0.f, rstd = 1.f;
  if (isLN) { mean = stats[i15 * 2]; rstd = stats[i15 * 2 + 1]; }
  long strip = rowbase >> 6;
  int mi = (rowbase >> 4) & 3;
  const float* srow = src + (long)i15 * HD;   // L1/L2-hot re-read (LN) or first read (W)
#pragma unroll
  for (int j = 0; j < 6; j++) {
    int kf = w * 6 + j;
    int c0 = kf * 32 + oct * 8;
    floatx4 v0 = *(const floatx4*)&srow[c0];
    floatx4 v1 = *(const floatx4*)&srow[c0 + 4];
    short8 pk;
#pragma unroll
    for (int e = 0; e < 8; e++) {
      float v = e < 4 ? v0[e] : v1[e - 4];
      float o = (v - mean) * rstd;
      if (isLN) o = o * g[c0 + e] + b[c0 + e];
      pk[e] = f2bf(o);
    }
    *(short8*)&dst[((strip * 24 + (long)kf) * 4 + mi) * 512 + (long)lane * 8] = pk;
  }
}

// ---------------- LDS-staged GEMM (m97 structure), EPI 0 (QKVU) / 1 (P) / 2 (G) ----
// 4 waves 2x2; wave tile (TM*16)x64; block (TM*32)x128. OCC = min waves/EU
// (= blocks/CU for 256-thread blocks).
template <int EPI, int KF, int GZ, int TM, int TN, int WN, int GY, int OCC>
__global__ __launch_bounds__(256, OCC) void wgemm(
    const short* __restrict__ Ag, const short* __restrict__ Bg,
    long sAz, long sBz,
    short* __restrict__ o0, short* __restrict__ o1,
    short* __restrict__ o2, short* __restrict__ o3,
    const float* __restrict__ bias, const short* __restrict__ umul) {
  constexpr int WM = 4 / WN;                 // 2
  constexpr int NSA = WM * TM / 4;           // A strips (TM=4: 2, TM=2: 1)
  constexpr int NSB = WN * TN / 4;           // 2 strips (BN = 128 cols)
  static_assert(TN == 4, "epilogue assumes TN=4");
  constexpr int LDSA_B = NSA * 4096 * 2;     // 2 buffers
  constexpr int LDSB_B = NSB * 4096 * 2;
  constexpr int SMEM_B = (LDSA_B + LDSB_B) < 32768 ? 32768 : (LDSA_B + LDSB_B);
  constexpr int GYX = (GZ == 1) ? GY / 8 : GY / 2;   // by-range per XCD
  int f = blockIdx.x;
  int xcd = f & 7, i = f >> 3;
  int bx = i / GYX, byo = i % GYX;
  int z, by;
  if constexpr (GZ == 1) { z = 0;        by = xcd * GYX + byo; }
  else                   { z = xcd >> 1; by = (xcd & 1) * GYX + byo; }

  int t = threadIdx.x, w = t >> 6, lane = t & 63;
  int qd = lane >> 4, l15 = lane & 15;
  int wm = w / WN, wn = w % WN;
  int mf0 = (by * WM + wm) * TM;               // frag-row index
  int nf0 = (bx * WN + wn) * TN;               // frag-col index

  __shared__ __align__(16) char smem[SMEM_B];

  const char* aG = (const char*)(Ag + (long)z * sAz) +
                   (long)(by * NSA) * KF * 4096 + w * 1024 + lane * 16;
  const char* bG = (const char*)(Bg + (long)z * sBz) +
                   (long)(bx * NSB) * KF * 4096 + w * 1024 + lane * 16;
  char* lA0 = smem + w * 1024;
  char* lB0 = smem + LDSA_B + w * 1024;

#define STAGE(p, kf)                                                          \
  {                                                                           \
    _Pragma("unroll") for (int s = 0; s < NSA; s++)                           \
        gload16(aG + ((long)s * KF + (kf)) * 4096,                            \
                lA0 + (p) * (NSA * 4096) + s * 4096);                         \
    _Pragma("unroll") for (int s = 0; s < NSB; s++)                           \
        gload16(bG + ((long)s * KF + (kf)) * 4096,                            \
                lB0 + (p) * (NSB * 4096) + s * 4096);                         \
  }

  floatx4 acc[TM][TN] = {};
  const char* fA = smem + (wm * TM) * 1024 + lane * 16;
  const char* fB = smem + LDSA_B + (wn * TN) * 1024 + lane * 16;

  STAGE(0, 0);
  __syncthreads();
#pragma unroll 2
  for (int kf = 0; kf < KF; ++kf) {
    int p = kf & 1;
    if (kf + 1 < KF) STAGE(p ^ 1, kf + 1);
    short8 a[TM], b[TN];
#pragma unroll
    for (int mi = 0; mi < TM; mi++)
      a[mi] = *(const short8*)(fA + p * (NSA * 4096) + mi * 1024);
#pragma unroll
    for (int ni = 0; ni < TN; ni++)
      b[ni] = *(const short8*)(fB + p * (NSB * 4096) + ni * 1024);
#pragma unroll
    for (int ni = 0; ni < TN; ni++)
#pragma unroll
      for (int mi = 0; mi < TM; mi++)
        acc[mi][ni] = __builtin_amdgcn_mfma_f32_16x16x32_bf16(
            a[mi], b[ni], acc[mi][ni], 0, 0, 0);
    __syncthreads();
  }
#undef STAGE

  // ---- epilogue ----
  int qd4 = qd * 4;
  if constexpr (EPI <= 1) {
    static_assert(EPI > 1 || TM == 4, "EPI0/1 assume TM=4");
    short* scw = (short*)(smem + w * 8192);        // 16 tiles x 512 B
    const bool vt = (EPI == 0) && (bx >= 18);      // which==3 (V): transposed tiles
#pragma unroll
    for (int mi = 0; mi < TM; mi++)
#pragma unroll
      for (int ni = 0; ni < TN; ni++) {
        int col = (nf0 + ni) * 16 + l15;
        short* tile = scw + (mi * TN + ni) * 256;
        short4v pk;
#pragma unroll
        for (int r = 0; r < 4; r++) {
          float v = acc[mi][ni][r];
          if constexpr (EPI == 0) {
            v += bias[col];
            v = v / (1.0f + __expf(-v));            // silu
          } else {
            v *= 0.022097086912079608f;             // 1/sqrt(2048)
            v = fmaxf(v, 0.0f);
            v = v * v;
          }
          short sv = f2bf(v);
          if (!vt) tile[(qd4 + r) * 16 + (l15 ^ (((qd4 + r) & 4) << 1))] = sv;
          else pk[r] = sv;
        }
        if (vt)   // transposed tile[col][row]; rows qd4..qd4+3 contiguous -> b64
          *(short4v*)&tile[l15 * 16 + (qd4 ^ ((l15 & 4) << 1))] = pk;
      }
    __syncthreads();
    int rw = lane & 15, g = (lane >> 4) & 1;
#pragma unroll
    for (int fp = 0; fp < 8; fp++) {
      int id = fp * 2 + (lane >> 5);
      int mi = id >> 2, ni = id & 3;
      const short* tile = scw + id * 256;
      short8 val = *(const short8*)&tile[rw * 16 + ((g ^ ((rw >> 2) & 1)) << 3)];
      if constexpr (EPI == 1) {
        int m = (mf0 + mi) * 16 + rw;
        int c0 = (nf0 + ni) * 16 + g * 8;
        *(short8*)&o0[(long)z * Ppb + pL(m, c0, 64)] = val;
      } else if (!vt) {
        int m = (mf0 + mi) * 16 + rw;
        int c0 = (nf0 + ni) * 16 + g * 8;
        int which = bx / 6;                      // block-uniform
        int d0 = c0 - which * HD;
        int batch = m >> 11, ii = m & (TT - 1);
        if (which == 0)      *(short8*)&o0[(long)m * HD + d0] = val;
        else if (which == 1) *(short8*)&o1[(long)batch * QKpb + pL(ii, d0, 24)] = val;
        else                 *(short8*)&o2[(long)batch * QKpb + pL(ii, d0, 24)] = val;
      } else {
        int d = (nf0 + ni) * 16 + rw - 3 * HD;   // tile row = original col
        int m0 = (mf0 + mi) * 16 + g * 8;        // 8 consecutive output rows
        int batch = m0 >> 11, ii0 = m0 & (TT - 1);
        *(short8*)&o3[(long)batch * QKpb + pL(d, ii0, 64)] = val;
      }
    }
  } else {
    // EPI 2: f32 scratch (no early rounding), TM/2 passes of 8 frags (8 KB/wave)
    float* scf = (float*)(smem + w * 8192);
#pragma unroll
    for (int half = 0; half < TM / 2; half++) {
#pragma unroll
      for (int mi2 = 0; mi2 < 2; mi2++)
#pragma unroll
        for (int ni = 0; ni < TN; ni++) {
          float* tile = scf + (mi2 * TN + ni) * 256;
          int mi = half * 2 + mi2;
#pragma unroll
          for (int r = 0; r < 4; r++)
            tile[(qd4 + r) * 16 + (l15 ^ (((qd4 + r) & 4) << 1))] = acc[mi][ni][r];
        }
      __syncthreads();
      int rw = lane & 15, g4 = lane >> 4;
#pragma unroll
      for (int cp = 0; cp < 8; cp++) {
        int mi = half * 2 + (cp >> 2), ni = cp & 3;
        const float* tile = scf + cp * 256;
        floatx4 val = *(const floatx4*)&tile[rw * 16 + ((g4 ^ (((rw >> 2) & 1) << 1)) << 2)];
        int m = (mf0 + mi) * 16 + rw;
        int c0 = (nf0 + ni) * 16 + g4 * 4;
        long gm = (long)z * TT + m;
        short4v u = *(const short4v*)&umul[gm * HD + c0];
        short4v gv;
#pragma unroll
        for (int j = 0; j < 4; j++) gv[j] = f2bf(val[j] * bf2f(u[j]));
        *(short4v*)&o0[pL((int)gm, c0, 24)] = gv;
      }
      __syncthreads();
    }
  }
}

// ---------------- barrier-free streaming GEMM (R0 verbatim) — 'out' only -----------
// 4 waves WM x WN; wave tile 64 x (TN*16); dist-2 ping-pong; ni-outer MFMA.
template <int KF, int TN, int WN, int GY>
__global__ __launch_bounds__(256, 3) void sgemm(
    const short* __restrict__ Ag, const short* __restrict__ Bg,
    float* __restrict__ outf, const float* __restrict__ bias) {
  constexpr int TM = 4;
  constexpr int GYX = GY / 8;                  // by-range per XCD
  int f = blockIdx.x;
  int xcd = f & 7, i = f >> 3;
  int bx = i / GYX, byo = i % GYX;
  int by = xcd * GYX + byo;

  int t = threadIdx.x, w = t >> 6, lane = t & 63;
  int qd = lane >> 4, l15 = lane & 15;
  int wm = w / WN, wn = w % WN;
  int mf0 = ((by * (4 / WN)) + wm) * TM;       // frag-row index (strip-aligned)
  int nf0 = (bx * WN + wn) * TN;               // frag-col index
  const short* aB = Ag + (long)(mf0 >> 2) * KF * 2048 + lane * 8;
  const short* bB = Bg + (long)(nf0 >> 2) * KF * 2048 + (nf0 & 3) * 512 + lane * 8;

  floatx4 acc[TM][TN] = {};
  short8 a[2][TM], b[2][TN];

#define LOADF(p, kf)                                                        \
  {                                                                         \
    _Pragma("unroll") for (int mi = 0; mi < TM; mi++)                       \
        a[p][mi] = *(const short8*)(aB + ((kf) * 4 + mi) * 512);            \
    _Pragma("unroll") for (int ni = 0; ni < TN; ni++)                       \
        b[p][ni] = *(const short8*)(bB + ((kf) * 4 + ni) * 512);            \
  }
#define MFMAS(p)                                                            \
  {                                                                         \
    _Pragma("unroll") for (int ni = 0; ni < TN; ni++)                       \
        _Pragma("unroll") for (int mi = 0; mi < TM; mi++)                   \
            acc[mi][ni] = __builtin_amdgcn_mfma_f32_16x16x32_bf16(          \
                a[p][mi], b[p][ni], acc[mi][ni], 0, 0, 0);                  \
  }

  LOADF(0, 0);
  LOADF(1, 1);
#pragma unroll 2
  for (int kf = 0; kf < KF; ++kf) {
    MFMAS(kf & 1);
    if (kf + 2 < KF) LOADF(kf & 1, kf + 2);   // refill the buffer just consumed
  }
#undef LOADF
#undef MFMAS

  // epilogue: lane holds D[row = qd*4+r][col = l15] per 16x16 frag
#pragma unroll
  for (int mi = 0; mi < TM; mi++)
#pragma unroll
    for (int ni = 0; ni < TN; ni++) {
      int mB = (mf0 + mi) * 16 + qd * 4;
      int col = (nf0 + ni) * 16 + l15;
#pragma unroll
      for (int r = 0; r < 4; r++) {
        int m = mB + r;
        outf[(long)m * HD + col] = acc[mi][ni][r] + bias[col];
      }
    }
}

extern "C" void kernel_launch(void* const* d_in, const int* in_sizes, int n_in,
                              void* d_out, int out_size, void* d_ws, size_t ws_size,
                              hipStream_t stream) {
  (void)in_sizes; (void)n_in; (void)out_size; (void)ws_size;
  const float* hid = (const float*)d_in[0];
  const float* lng = (const float*)d_in[1];
  const float* lnb = (const float*)d_in[2];
  const float* Wu  = (const float*)d_in[3];
  const float* bu  = (const float*)d_in[4];
  const float* Wq  = (const float*)d_in[5];
  const float* bq  = (const float*)d_in[6];
  const float* Wk  = (const float*)d_in[7];
  const float* bk  = (const float*)d_in[8];
  const float* Wv  = (const float*)d_in[9];
  const float* bv  = (const float*)d_in[10];
  const float* Wo  = (const float*)d_in[11];
  const float* bo  = (const float*)d_in[12];

  // workspace layout (bytes); packed buffers
  char* ws = (char*)d_ws;
  short* Wb   = (short*)(ws);                 // 5*589824 bf16 = 5,898,240 B (packed)
  float* bcat = (float*)(ws + 5898240);       // 3072 fp32     =    12,288 B
  short* xbf  = (short*)(ws + 5910528);       // x pack, 12,582,912 B
  short* Ub   = (short*)(ws + 18493440);      // U row-major, 12,582,912 B
  short* Qb   = (short*)(ws + 31076352);      // Q pack, 12,582,912 B
  short* Kb   = (short*)(ws + 43659264);      // K pack, 12,582,912 B
  short* Vt   = (short*)(ws + 56242176);      // Vt pack, 12,582,912 B
  short* Pb   = (short*)(ws + 68825088);      // P pack, 33,554,432 B
  short* Gb   = (short*)(ws + 102379520);     // G pack, 12,582,912 B (total ~115 MB)

  // preprocessing: [0,512) LN slabs, [512,752) weight slabs, 752 bias
  pre_kernel<<<753, 256, 0, stream>>>(hid, lng, lnb, xbf,
      Wu, Wq, Wk, Wv, Wo, bu, bq, bk, bv, Wb, bcat);

  // U,Q,K,V = silu(x @ Wcat^T + bcat): block 128x128 (TM=4) @4/CU, GY=64, GX=24
  wgemm<0, 24, 1, 4, 4, 2, 64, 4><<<1536, 256, 0, stream>>>(
      xbf, Wb, 0, 0, Ub, Qb, Kb, Vt, bcat, nullptr);

  // P = relu(QK^T/sqrt(T))^2 per batch: 2-phase 128x128 @4/CU, GY=16, GX=16, GZ=4
  wgemm<1, 24, 4, 4, 4, 2, 16, 4><<<1024, 256, 0, stream>>>(
      Qb, Kb, QKpb, QKpb, Pb, nullptr, nullptr, nullptr, nullptr, nullptr);

  // G = (P @ V) * U per batch: staged 64x128 (TM=2) @4/CU, GY=32, GX=6, GZ=4 -> 768
  wgemm<2, 64, 4, 2, 4, 2, 32, 4><<<768, 256, 0, stream>>>(
      Pb, Vt, Ppb, QKpb, Gb, nullptr, nullptr, nullptr, nullptr, Ub);

  // out = G @ Wo^T + bo: STREAMING, block 128x64 (2x2, TN=2), GY=64, GX=12
  sgemm<24, 2, 2, 64><<<768, 256, 0, stream>>>(
      Gb, Wb + 4 * WElem, (float*)d_out, bo);
}

// Round 10
// 237.281 us; speedup vs baseline: 1.0583x; 1.0583x over previous
//
#include <hip/hip_runtime.h>
#include <math.h>

// GAU attention: LN -> silu(x@W^T+b) x4 -> P=relu^2(QK^T/sqrt(T)) -> AV=P@V -> (U*AV)@Wo^T+bo
// R21: recombine measured-best occupancy per kernel. R20 falsified "OCC=4 helps
// everywhere": QKVU @4 regressed 52->85us (T_block x2.2 — vmem-queue contention:
// 16 waves x 8 outstanding global_load_lds/kf saturate the queue; plus 1536 blocks
// = 1.5 messy rounds @4 vs 2 clean @3). But accounting (dTotal +9.8 vs dQKVU +33)
// shows G @4 gained ~20-23us (768 blocks all-resident, lighter 12KB/2-kf staging).
//  - QKVU: OCC=3 (proven 52us). P: OCC=4 (R19). G: OCC=4 (R20). Single variable.
//  - out (streaming), pre (slab pack): unchanged.

typedef __attribute__((ext_vector_type(8))) short short8;
typedef __attribute__((ext_vector_type(4))) short short4v;
typedef __attribute__((ext_vector_type(4))) float floatx4;

constexpr int HD = 768;
constexpr int TT = 2048;
constexpr long WElem = 589824;     // 768*768
constexpr long QKpb  = 1572864;    // 2048*768 shorts per batch
constexpr long Ppb   = 4194304;    // 2048*2048 shorts per batch

__device__ __forceinline__ short f2bf(float x) {
  unsigned u = __builtin_bit_cast(unsigned, x);
  u = u + 0x7fffu + ((u >> 16) & 1u);   // RNE
  return (short)(u >> 16);
}
__device__ __forceinline__ float bf2f(short s) {
  unsigned u = ((unsigned)(unsigned short)s) << 16;
  return __builtin_bit_cast(float, u);
}

// kf-major packed offset (in shorts) of element (i, c) of a row-major [R x C]
// matrix, KF = C/32. Layout: [strip = i>>6][kf = c>>5][frag mi = (i>>4)&3][512].
// Within-frag: lane = ((c&31)>>3)*16 + (i&15), elem = c&7.
__device__ __forceinline__ long pL(int i, int c, int KF) {
  return (((long)(i >> 6) * KF + (c >> 5)) * 4 + ((i >> 4) & 3)) * 512 +
         ((c & 31) >> 3) * 128 + (i & 15) * 8 + (c & 7);
}

typedef __attribute__((address_space(1))) void void_g;
typedef __attribute__((address_space(3))) void void_l;
__device__ __forceinline__ void gload16(const void* g, void* l) {
  __builtin_amdgcn_global_load_lds((const void_g*)g, (void_l*)l, 16, 0, 0);
}

// ---------------- preprocessing: 16-row slabs, whole-frag coalesced writes ---------
// blocks [0,512): LN slabs of x (16 rows each); [512,752): weight slabs; 752: bias.
__global__ __launch_bounds__(256) void pre_kernel(
    const float* __restrict__ x, const float* __restrict__ g,
    const float* __restrict__ b, short* __restrict__ out,
    const float* __restrict__ wu, const float* __restrict__ wq,
    const float* __restrict__ wk, const float* __restrict__ wv,
    const float* __restrict__ wo,
    const float* __restrict__ bu, const float* __restrict__ bq,
    const float* __restrict__ bk, const float* __restrict__ bv,
    short* __restrict__ Wb, float* __restrict__ bcat) {
  int t = threadIdx.x;
  int bid = blockIdx.x;
  if (bid == 752) {                      // bias concat
#pragma unroll
    for (int j = 0; j < 12; j++) {
      int i = j * 256 + t;
      int which = i / HD, off = i - which * HD;
      const float* src = which == 0 ? bu : which == 1 ? bq : which == 2 ? bk : bv;
      bcat[i] = src[off];
    }
    return;
  }
  bool isLN = bid < 512;
  const float* src; short* dst; int rowbase;
  if (isLN) {
    rowbase = bid * 16; src = x + (long)rowbase * HD; dst = out;
  } else {
    int wb = bid - 512, which = wb / 48, rg = wb - which * 48;
    rowbase = rg * 16;
    src = (which == 0 ? wu : which == 1 ? wq : which == 2 ? wk
         : which == 3 ? wv : wo) + (long)rowbase * HD;
    dst = Wb + (long)which * WElem;
  }
  int lane = t & 63, w = t >> 6;
  __shared__ float stats[32];
  if (isLN) {
    int r = t >> 4, q = t & 15;          // 16 lanes per row
    float s = 0.f, ss = 0.f;
#pragma unroll
    for (int j = 0; j < 12; j++) {
      floatx4 v = *(const floatx4*)&src[(long)r * HD + q * 4 + j * 64];
#pragma unroll
      for (int e = 0; e < 4; e++) { s += v[e]; ss += v[e] * v[e]; }
    }
#pragma unroll
    for (int m = 1; m < 16; m <<= 1) {
      s += __shfl_xor(s, m); ss += __shfl_xor(ss, m);
    }
    if (q == 0) {
      float mean = s * (1.0f / HD);
      float var = ss * (1.0f / HD) - mean * mean;
      stats[r * 2] = mean;
      stats[r * 2 + 1] = rsqrtf(var + 1e-5f);
    }
    __syncthreads();
  }
  int oct = lane >> 4, i15 = lane & 15;
  float mean = 0.f, rstd = 1.f;
  if (isLN) { mean = stats[i15 * 2]; rstd = stats[i15 * 2 + 1]; }
  long strip = rowbase >> 6;
  int mi = (rowbase >> 4) & 3;
  const float* srow = src + (long)i15 * HD;   // L1/L2-hot re-read (LN) or first read (W)
#pragma unroll
  for (int j = 0; j < 6; j++) {
    int kf = w * 6 + j;
    int c0 = kf * 32 + oct * 8;
    floatx4 v0 = *(const floatx4*)&srow[c0];
    floatx4 v1 = *(const floatx4*)&srow[c0 + 4];
    short8 pk;
#pragma unroll
    for (int e = 0; e < 8; e++) {
      float v = e < 4 ? v0[e] : v1[e - 4];
      float o = (v - mean) * rstd;
      if (isLN) o = o * g[c0 + e] + b[c0 + e];
      pk[e] = f2bf(o);
    }
    *(short8*)&dst[((strip * 24 + (long)kf) * 4 + mi) * 512 + (long)lane * 8] = pk;
  }
}

// ---------------- LDS-staged GEMM (m97 structure), EPI 0 (QKVU) / 1 (P) / 2 (G) ----
// 4 waves 2x2; wave tile (TM*16)x64; block (TM*32)x128. OCC = min waves/EU
// (= blocks/CU for 256-thread blocks).
template <int EPI, int KF, int GZ, int TM, int TN, int WN, int GY, int OCC>
__global__ __launch_bounds__(256, OCC) void wgemm(
    const short* __restrict__ Ag, const short* __restrict__ Bg,
    long sAz, long sBz,
    short* __restrict__ o0, short* __restrict__ o1,
    short* __restrict__ o2, short* __restrict__ o3,
    const float* __restrict__ bias, const short* __restrict__ umul) {
  constexpr int WM = 4 / WN;                 // 2
  constexpr int NSA = WM * TM / 4;           // A strips (TM=4: 2, TM=2: 1)
  constexpr int NSB = WN * TN / 4;           // 2 strips (BN = 128 cols)
  static_assert(TN == 4, "epilogue assumes TN=4");
  constexpr int LDSA_B = NSA * 4096 * 2;     // 2 buffers
  constexpr int LDSB_B = NSB * 4096 * 2;
  constexpr int SMEM_B = (LDSA_B + LDSB_B) < 32768 ? 32768 : (LDSA_B + LDSB_B);
  constexpr int GYX = (GZ == 1) ? GY / 8 : GY / 2;   // by-range per XCD
  int f = blockIdx.x;
  int xcd = f & 7, i = f >> 3;
  int bx = i / GYX, byo = i % GYX;
  int z, by;
  if constexpr (GZ == 1) { z = 0;        by = xcd * GYX + byo; }
  else                   { z = xcd >> 1; by = (xcd & 1) * GYX + byo; }

  int t = threadIdx.x, w = t >> 6, lane = t & 63;
  int qd = lane >> 4, l15 = lane & 15;
  int wm = w / WN, wn = w % WN;
  int mf0 = (by * WM + wm) * TM;               // frag-row index
  int nf0 = (bx * WN + wn) * TN;               // frag-col index

  __shared__ __align__(16) char smem[SMEM_B];

  const char* aG = (const char*)(Ag + (long)z * sAz) +
                   (long)(by * NSA) * KF * 4096 + w * 1024 + lane * 16;
  const char* bG = (const char*)(Bg + (long)z * sBz) +
                   (long)(bx * NSB) * KF * 4096 + w * 1024 + lane * 16;
  char* lA0 = smem + w * 1024;
  char* lB0 = smem + LDSA_B + w * 1024;

#define STAGE(p, kf)                                                          \
  {                                                                           \
    _Pragma("unroll") for (int s = 0; s < NSA; s++)                           \
        gload16(aG + ((long)s * KF + (kf)) * 4096,                            \
                lA0 + (p) * (NSA * 4096) + s * 4096);                         \
    _Pragma("unroll") for (int s = 0; s < NSB; s++)                           \
        gload16(bG + ((long)s * KF + (kf)) * 4096,                            \
                lB0 + (p) * (NSB * 4096) + s * 4096);                         \
  }

  floatx4 acc[TM][TN] = {};
  const char* fA = smem + (wm * TM) * 1024 + lane * 16;
  const char* fB = smem + LDSA_B + (wn * TN) * 1024 + lane * 16;

  STAGE(0, 0);
  __syncthreads();
#pragma unroll 2
  for (int kf = 0; kf < KF; ++kf) {
    int p = kf & 1;
    if (kf + 1 < KF) STAGE(p ^ 1, kf + 1);
    short8 a[TM], b[TN];
#pragma unroll
    for (int mi = 0; mi < TM; mi++)
      a[mi] = *(const short8*)(fA + p * (NSA * 4096) + mi * 1024);
#pragma unroll
    for (int ni = 0; ni < TN; ni++)
      b[ni] = *(const short8*)(fB + p * (NSB * 4096) + ni * 1024);
#pragma unroll
    for (int ni = 0; ni < TN; ni++)
#pragma unroll
      for (int mi = 0; mi < TM; mi++)
        acc[mi][ni] = __builtin_amdgcn_mfma_f32_16x16x32_bf16(
            a[mi], b[ni], acc[mi][ni], 0, 0, 0);
    __syncthreads();
  }
#undef STAGE

  // ---- epilogue ----
  int qd4 = qd * 4;
  if constexpr (EPI <= 1) {
    static_assert(EPI > 1 || TM == 4, "EPI0/1 assume TM=4");
    short* scw = (short*)(smem + w * 8192);        // 16 tiles x 512 B
    const bool vt = (EPI == 0) && (bx >= 18);      // which==3 (V): transposed tiles
#pragma unroll
    for (int mi = 0; mi < TM; mi++)
#pragma unroll
      for (int ni = 0; ni < TN; ni++) {
        int col = (nf0 + ni) * 16 + l15;
        short* tile = scw + (mi * TN + ni) * 256;
        short4v pk;
#pragma unroll
        for (int r = 0; r < 4; r++) {
          float v = acc[mi][ni][r];
          if constexpr (EPI == 0) {
            v += bias[col];
            v = v / (1.0f + __expf(-v));            // silu
          } else {
            v *= 0.022097086912079608f;             // 1/sqrt(2048)
            v = fmaxf(v, 0.0f);
            v = v * v;
          }
          short sv = f2bf(v);
          if (!vt) tile[(qd4 + r) * 16 + (l15 ^ (((qd4 + r) & 4) << 1))] = sv;
          else pk[r] = sv;
        }
        if (vt)   // transposed tile[col][row]; rows qd4..qd4+3 contiguous -> b64
          *(short4v*)&tile[l15 * 16 + (qd4 ^ ((l15 & 4) << 1))] = pk;
      }
    __syncthreads();
    int rw = lane & 15, g = (lane >> 4) & 1;
#pragma unroll
    for (int fp = 0; fp < 8; fp++) {
      int id = fp * 2 + (lane >> 5);
      int mi = id >> 2, ni = id & 3;
      const short* tile = scw + id * 256;
      short8 val = *(const short8*)&tile[rw * 16 + ((g ^ ((rw >> 2) & 1)) << 3)];
      if constexpr (EPI == 1) {
        int m = (mf0 + mi) * 16 + rw;
        int c0 = (nf0 + ni) * 16 + g * 8;
        *(short8*)&o0[(long)z * Ppb + pL(m, c0, 64)] = val;
      } else if (!vt) {
        int m = (mf0 + mi) * 16 + rw;
        int c0 = (nf0 + ni) * 16 + g * 8;
        int which = bx / 6;                      // block-uniform
        int d0 = c0 - which * HD;
        int batch = m >> 11, ii = m & (TT - 1);
        if (which == 0)      *(short8*)&o0[(long)m * HD + d0] = val;
        else if (which == 1) *(short8*)&o1[(long)batch * QKpb + pL(ii, d0, 24)] = val;
        else                 *(short8*)&o2[(long)batch * QKpb + pL(ii, d0, 24)] = val;
      } else {
        int d = (nf0 + ni) * 16 + rw - 3 * HD;   // tile row = original col
        int m0 = (mf0 + mi) * 16 + g * 8;        // 8 consecutive output rows
        int batch = m0 >> 11, ii0 = m0 & (TT - 1);
        *(short8*)&o3[(long)batch * QKpb + pL(d, ii0, 64)] = val;
      }
    }
  } else {
    // EPI 2: f32 scratch (no early rounding), TM/2 passes of 8 frags (8 KB/wave)
    float* scf = (float*)(smem + w * 8192);
#pragma unroll
    for (int half = 0; half < TM / 2; half++) {
#pragma unroll
      for (int mi2 = 0; mi2 < 2; mi2++)
#pragma unroll
        for (int ni = 0; ni < TN; ni++) {
          float* tile = scf + (mi2 * TN + ni) * 256;
          int mi = half * 2 + mi2;
#pragma unroll
          for (int r = 0; r < 4; r++)
            tile[(qd4 + r) * 16 + (l15 ^ (((qd4 + r) & 4) << 1))] = acc[mi][ni][r];
        }
      __syncthreads();
      int rw = lane & 15, g4 = lane >> 4;
#pragma unroll
      for (int cp = 0; cp < 8; cp++) {
        int mi = half * 2 + (cp >> 2), ni = cp & 3;
        const float* tile = scf + cp * 256;
        floatx4 val = *(const floatx4*)&tile[rw * 16 + ((g4 ^ (((rw >> 2) & 1) << 1)) << 2)];
        int m = (mf0 + mi) * 16 + rw;
        int c0 = (nf0 + ni) * 16 + g4 * 4;
        long gm = (long)z * TT + m;
        short4v u = *(const short4v*)&umul[gm * HD + c0];
        short4v gv;
#pragma unroll
        for (int j = 0; j < 4; j++) gv[j] = f2bf(val[j] * bf2f(u[j]));
        *(short4v*)&o0[pL((int)gm, c0, 24)] = gv;
      }
      __syncthreads();
    }
  }
}

// ---------------- barrier-free streaming GEMM (R0 verbatim) — 'out' only -----------
// 4 waves WM x WN; wave tile 64 x (TN*16); dist-2 ping-pong; ni-outer MFMA.
template <int KF, int TN, int WN, int GY>
__global__ __launch_bounds__(256, 3) void sgemm(
    const short* __restrict__ Ag, const short* __restrict__ Bg,
    float* __restrict__ outf, const float* __restrict__ bias) {
  constexpr int TM = 4;
  constexpr int GYX = GY / 8;                  // by-range per XCD
  int f = blockIdx.x;
  int xcd = f & 7, i = f >> 3;
  int bx = i / GYX, byo = i % GYX;
  int by = xcd * GYX + byo;

  int t = threadIdx.x, w = t >> 6, lane = t & 63;
  int qd = lane >> 4, l15 = lane & 15;
  int wm = w / WN, wn = w % WN;
  int mf0 = ((by * (4 / WN)) + wm) * TM;       // frag-row index (strip-aligned)
  int nf0 = (bx * WN + wn) * TN;               // frag-col index
  const short* aB = Ag + (long)(mf0 >> 2) * KF * 2048 + lane * 8;
  const short* bB = Bg + (long)(nf0 >> 2) * KF * 2048 + (nf0 & 3) * 512 + lane * 8;

  floatx4 acc[TM][TN] = {};
  short8 a[2][TM], b[2][TN];

#define LOADF(p, kf)                                                        \
  {                                                                         \
    _Pragma("unroll") for (int mi = 0; mi < TM; mi++)                       \
        a[p][mi] = *(const short8*)(aB + ((kf) * 4 + mi) * 512);            \
    _Pragma("unroll") for (int ni = 0; ni < TN; ni++)                       \
        b[p][ni] = *(const short8*)(bB + ((kf) * 4 + ni) * 512);            \
  }
#define MFMAS(p)                                                            \
  {                                                                         \
    _Pragma("unroll") for (int ni = 0; ni < TN; ni++)                       \
        _Pragma("unroll") for (int mi = 0; mi < TM; mi++)                   \
            acc[mi][ni] = __builtin_amdgcn_mfma_f32_16x16x32_bf16(          \
                a[p][mi], b[p][ni], acc[mi][ni], 0, 0, 0);                  \
  }

  LOADF(0, 0);
  LOADF(1, 1);
#pragma unroll 2
  for (int kf = 0; kf < KF; ++kf) {
    MFMAS(kf & 1);
    if (kf + 2 < KF) LOADF(kf & 1, kf + 2);   // refill the buffer just consumed
  }
#undef LOADF
#undef MFMAS

  // epilogue: lane holds D[row = qd*4+r][col = l15] per 16x16 frag
#pragma unroll
  for (int mi = 0; mi < TM; mi++)
#pragma unroll
    for (int ni = 0; ni < TN; ni++) {
      int mB = (mf0 + mi) * 16 + qd * 4;
      int col = (nf0 + ni) * 16 + l15;
#pragma unroll
      for (int r = 0; r < 4; r++) {
        int m = mB + r;
        outf[(long)m * HD + col] = acc[mi][ni][r] + bias[col];
      }
    }
}

extern "C" void kernel_launch(void* const* d_in, const int* in_sizes, int n_in,
                              void* d_out, int out_size, void* d_ws, size_t ws_size,
                              hipStream_t stream) {
  (void)in_sizes; (void)n_in; (void)out_size; (void)ws_size;
  const float* hid = (const float*)d_in[0];
  const float* lng = (const float*)d_in[1];
  const float* lnb = (const float*)d_in[2];
  const float* Wu  = (const float*)d_in[3];
  const float* bu  = (const float*)d_in[4];
  const float* Wq  = (const float*)d_in[5];
  const float* bq  = (const float*)d_in[6];
  const float* Wk  = (const float*)d_in[7];
  const float* bk  = (const float*)d_in[8];
  const float* Wv  = (const float*)d_in[9];
  const float* bv  = (const float*)d_in[10];
  const float* Wo  = (const float*)d_in[11];
  const float* bo  = (const float*)d_in[12];

  // workspace layout (bytes); packed buffers
  char* ws = (char*)d_ws;
  short* Wb   = (short*)(ws);                 // 5*589824 bf16 = 5,898,240 B (packed)
  float* bcat = (float*)(ws + 5898240);       // 3072 fp32     =    12,288 B
  short* xbf  = (short*)(ws + 5910528);       // x pack, 12,582,912 B
  short* Ub   = (short*)(ws + 18493440);      // U row-major, 12,582,912 B
  short* Qb   = (short*)(ws + 31076352);      // Q pack, 12,582,912 B
  short* Kb   = (short*)(ws + 43659264);      // K pack, 12,582,912 B
  short* Vt   = (short*)(ws + 56242176);      // Vt pack, 12,582,912 B
  short* Pb   = (short*)(ws + 68825088);      // P pack, 33,554,432 B
  short* Gb   = (short*)(ws + 102379520);     // G pack, 12,582,912 B (total ~115 MB)

  // preprocessing: [0,512) LN slabs, [512,752) weight slabs, 752 bias
  pre_kernel<<<753, 256, 0, stream>>>(hid, lng, lnb, xbf,
      Wu, Wq, Wk, Wv, Wo, bu, bq, bk, bv, Wb, bcat);

  // U,Q,K,V = silu(x @ Wcat^T + bcat): block 128x128 (TM=4) @3/CU, GY=64, GX=24
  wgemm<0, 24, 1, 4, 4, 2, 64, 3><<<1536, 256, 0, stream>>>(
      xbf, Wb, 0, 0, Ub, Qb, Kb, Vt, bcat, nullptr);

  // P = relu(QK^T/sqrt(T))^2 per batch: 2-phase 128x128 @4/CU, GY=16, GX=16, GZ=4
  wgemm<1, 24, 4, 4, 4, 2, 16, 4><<<1024, 256, 0, stream>>>(
      Qb, Kb, QKpb, QKpb, Pb, nullptr, nullptr, nullptr, nullptr, nullptr);

  // G = (P @ V) * U per batch: staged 64x128 (TM=2) @4/CU, GY=32, GX=6, GZ=4 -> 768
  wgemm<2, 64, 4, 2, 4, 2, 32, 4><<<768, 256, 0, stream>>>(
      Pb, Vt, Ppb, QKpb, Gb, nullptr, nullptr, nullptr, nullptr, Ub);

  // out = G @ Wo^T + bo: STREAMING, block 128x64 (2x2, TN=2), GY=64, GX=12
  sgemm<24, 2, 2, 64><<<768, 256, 0, stream>>>(
      Gb, Wb + 4 * WElem, (float*)d_out, bo);
}

// Round 11
// 234.289 us; speedup vs baseline: 1.0718x; 1.0128x over previous
//
#include <hip/hip_runtime.h>
#include <math.h>

// GAU attention: LN -> silu(x@W^T+b) x4 -> P=relu^2(QK^T/sqrt(T)) -> AV=P@V -> (U*AV)@Wo^T+bo
// R22: out -> staged wgemm in G's proven geometry. Streaming out loads 6KB/wave/kf
// from L2 for 8 MFMAs (L2-supply-bound, ~200-300 TF) -> 9.7 GFLOP costs ~35-45us.
// Staged TM=2 (64x128) @768 blocks @OCC=4 (exactly G's working config) should run
// ~570 TF -> ~15-20us. R15/16's staged-out failure was TM=4@384@OCC3 (bad packing,
// since diagnosed+fixed via G). EPI=3 = EPI2's f32-scratch epilogue with +bias and
// coalesced float4 stores. Single variable; QKVU/P/G/pre unchanged from R21.
//  - occupancy map (measured): QKVU OCC=3 (R20: @4 = vmem-queue collapse, 52->85us),
//    P OCC=4 (R19: +6us), G OCC=4 (R19vR21 A/B: -4us).

typedef __attribute__((ext_vector_type(8))) short short8;
typedef __attribute__((ext_vector_type(4))) short short4v;
typedef __attribute__((ext_vector_type(4))) float floatx4;

constexpr int HD = 768;
constexpr int TT = 2048;
constexpr long WElem = 589824;     // 768*768
constexpr long QKpb  = 1572864;    // 2048*768 shorts per batch
constexpr long Ppb   = 4194304;    // 2048*2048 shorts per batch

__device__ __forceinline__ short f2bf(float x) {
  unsigned u = __builtin_bit_cast(unsigned, x);
  u = u + 0x7fffu + ((u >> 16) & 1u);   // RNE
  return (short)(u >> 16);
}
__device__ __forceinline__ float bf2f(short s) {
  unsigned u = ((unsigned)(unsigned short)s) << 16;
  return __builtin_bit_cast(float, u);
}

// kf-major packed offset (in shorts) of element (i, c) of a row-major [R x C]
// matrix, KF = C/32. Layout: [strip = i>>6][kf = c>>5][frag mi = (i>>4)&3][512].
// Within-frag: lane = ((c&31)>>3)*16 + (i&15), elem = c&7.
__device__ __forceinline__ long pL(int i, int c, int KF) {
  return (((long)(i >> 6) * KF + (c >> 5)) * 4 + ((i >> 4) & 3)) * 512 +
         ((c & 31) >> 3) * 128 + (i & 15) * 8 + (c & 7);
}

typedef __attribute__((address_space(1))) void void_g;
typedef __attribute__((address_space(3))) void void_l;
__device__ __forceinline__ void gload16(const void* g, void* l) {
  __builtin_amdgcn_global_load_lds((const void_g*)g, (void_l*)l, 16, 0, 0);
}

// ---------------- preprocessing: 16-row slabs, whole-frag coalesced writes ---------
// blocks [0,512): LN slabs of x (16 rows each); [512,752): weight slabs; 752: bias.
__global__ __launch_bounds__(256) void pre_kernel(
    const float* __restrict__ x, const float* __restrict__ g,
    const float* __restrict__ b, short* __restrict__ out,
    const float* __restrict__ wu, const float* __restrict__ wq,
    const float* __restrict__ wk, const float* __restrict__ wv,
    const float* __restrict__ wo,
    const float* __restrict__ bu, const float* __restrict__ bq,
    const float* __restrict__ bk, const float* __restrict__ bv,
    short* __restrict__ Wb, float* __restrict__ bcat) {
  int t = threadIdx.x;
  int bid = blockIdx.x;
  if (bid == 752) {                      // bias concat
#pragma unroll
    for (int j = 0; j < 12; j++) {
      int i = j * 256 + t;
      int which = i / HD, off = i - which * HD;
      const float* src = which == 0 ? bu : which == 1 ? bq : which == 2 ? bk : bv;
      bcat[i] = src[off];
    }
    return;
  }
  bool isLN = bid < 512;
  const float* src; short* dst; int rowbase;
  if (isLN) {
    rowbase = bid * 16; src = x + (long)rowbase * HD; dst = out;
  } else {
    int wb = bid - 512, which = wb / 48, rg = wb - which * 48;
    rowbase = rg * 16;
    src = (which == 0 ? wu : which == 1 ? wq : which == 2 ? wk
         : which == 3 ? wv : wo) + (long)rowbase * HD;
    dst = Wb + (long)which * WElem;
  }
  int lane = t & 63, w = t >> 6;
  __shared__ float stats[32];
  if (isLN) {
    int r = t >> 4, q = t & 15;          // 16 lanes per row
    float s = 0.f, ss = 0.f;
#pragma unroll
    for (int j = 0; j < 12; j++) {
      floatx4 v = *(const floatx4*)&src[(long)r * HD + q * 4 + j * 64];
#pragma unroll
      for (int e = 0; e < 4; e++) { s += v[e]; ss += v[e] * v[e]; }
    }
#pragma unroll
    for (int m = 1; m < 16; m <<= 1) {
      s += __shfl_xor(s, m); ss += __shfl_xor(ss, m);
    }
    if (q == 0) {
      float mean = s * (1.0f / HD);
      float var = ss * (1.0f / HD) - mean * mean;
      stats[r * 2] = mean;
      stats[r * 2 + 1] = rsqrtf(var + 1e-5f);
    }
    __syncthreads();
  }
  int oct = lane >> 4, i15 = lane & 15;
  float mean = 0.f, rstd = 1.f;
  if (isLN) { mean = stats[i15 * 2]; rstd = stats[i15 * 2 + 1]; }
  long strip = rowbase >> 6;
  int mi = (rowbase >> 4) & 3;
  const float* srow = src + (long)i15 * HD;   // L1/L2-hot re-read (LN) or first read (W)
#pragma unroll
  for (int j = 0; j < 6; j++) {
    int kf = w * 6 + j;
    int c0 = kf * 32 + oct * 8;
    floatx4 v0 = *(const floatx4*)&srow[c0];
    floatx4 v1 = *(const floatx4*)&srow[c0 + 4];
    short8 pk;
#pragma unroll
    for (int e = 0; e < 8; e++) {
      float v = e < 4 ? v0[e] : v1[e - 4];
      float o = (v - mean) * rstd;
      if (isLN) o = o * g[c0 + e] + b[c0 + e];
      pk[e] = f2bf(o);
    }
    *(short8*)&dst[((strip * 24 + (long)kf) * 4 + mi) * 512 + (long)lane * 8] = pk;
  }
}

// ---------------- LDS-staged GEMM (m97 structure) ----------------------------------
// EPI 0: QKVU (silu+bias, split outputs). EPI 1: P (relu^2). EPI 2: G (*U, packed).
// EPI 3: out (fp32 +bias). 4 waves 2x2; wave tile (TM*16)x64; block (TM*32)x128.
// OCC = min waves/EU (= blocks/CU for 256-thread blocks).
template <int EPI, int KF, int GZ, int TM, int TN, int WN, int GY, int OCC>
__global__ __launch_bounds__(256, OCC) void wgemm(
    const short* __restrict__ Ag, const short* __restrict__ Bg,
    long sAz, long sBz,
    short* __restrict__ o0, short* __restrict__ o1,
    short* __restrict__ o2, short* __restrict__ o3,
    float* __restrict__ outf, const float* __restrict__ bias,
    const short* __restrict__ umul) {
  constexpr int WM = 4 / WN;                 // 2
  constexpr int NSA = WM * TM / 4;           // A strips (TM=4: 2, TM=2: 1)
  constexpr int NSB = WN * TN / 4;           // 2 strips (BN = 128 cols)
  static_assert(TN == 4, "epilogue assumes TN=4");
  constexpr int LDSA_B = NSA * 4096 * 2;     // 2 buffers
  constexpr int LDSB_B = NSB * 4096 * 2;
  constexpr int SMEM_B = (LDSA_B + LDSB_B) < 32768 ? 32768 : (LDSA_B + LDSB_B);
  constexpr int GYX = (GZ == 1) ? GY / 8 : GY / 2;   // by-range per XCD
  int f = blockIdx.x;
  int xcd = f & 7, i = f >> 3;
  int bx = i / GYX, byo = i % GYX;
  int z, by;
  if constexpr (GZ == 1) { z = 0;        by = xcd * GYX + byo; }
  else                   { z = xcd >> 1; by = (xcd & 1) * GYX + byo; }

  int t = threadIdx.x, w = t >> 6, lane = t & 63;
  int qd = lane >> 4, l15 = lane & 15;
  int wm = w / WN, wn = w % WN;
  int mf0 = (by * WM + wm) * TM;               // frag-row index
  int nf0 = (bx * WN + wn) * TN;               // frag-col index

  __shared__ __align__(16) char smem[SMEM_B];

  const char* aG = (const char*)(Ag + (long)z * sAz) +
                   (long)(by * NSA) * KF * 4096 + w * 1024 + lane * 16;
  const char* bG = (const char*)(Bg + (long)z * sBz) +
                   (long)(bx * NSB) * KF * 4096 + w * 1024 + lane * 16;
  char* lA0 = smem + w * 1024;
  char* lB0 = smem + LDSA_B + w * 1024;

#define STAGE(p, kf)                                                          \
  {                                                                           \
    _Pragma("unroll") for (int s = 0; s < NSA; s++)                           \
        gload16(aG + ((long)s * KF + (kf)) * 4096,                            \
                lA0 + (p) * (NSA * 4096) + s * 4096);                         \
    _Pragma("unroll") for (int s = 0; s < NSB; s++)                           \
        gload16(bG + ((long)s * KF + (kf)) * 4096,                            \
                lB0 + (p) * (NSB * 4096) + s * 4096);                         \
  }

  floatx4 acc[TM][TN] = {};
  const char* fA = smem + (wm * TM) * 1024 + lane * 16;
  const char* fB = smem + LDSA_B + (wn * TN) * 1024 + lane * 16;

  STAGE(0, 0);
  __syncthreads();
#pragma unroll 2
  for (int kf = 0; kf < KF; ++kf) {
    int p = kf & 1;
    if (kf + 1 < KF) STAGE(p ^ 1, kf + 1);
    short8 a[TM], b[TN];
#pragma unroll
    for (int mi = 0; mi < TM; mi++)
      a[mi] = *(const short8*)(fA + p * (NSA * 4096) + mi * 1024);
#pragma unroll
    for (int ni = 0; ni < TN; ni++)
      b[ni] = *(const short8*)(fB + p * (NSB * 4096) + ni * 1024);
#pragma unroll
    for (int ni = 0; ni < TN; ni++)
#pragma unroll
      for (int mi = 0; mi < TM; mi++)
        acc[mi][ni] = __builtin_amdgcn_mfma_f32_16x16x32_bf16(
            a[mi], b[ni], acc[mi][ni], 0, 0, 0);
    __syncthreads();
  }
#undef STAGE

  // ---- epilogue ----
  int qd4 = qd * 4;
  if constexpr (EPI <= 1) {
    static_assert(EPI > 1 || TM == 4, "EPI0/1 assume TM=4");
    short* scw = (short*)(smem + w * 8192);        // 16 tiles x 512 B
    const bool vt = (EPI == 0) && (bx >= 18);      // which==3 (V): transposed tiles
#pragma unroll
    for (int mi = 0; mi < TM; mi++)
#pragma unroll
      for (int ni = 0; ni < TN; ni++) {
        int col = (nf0 + ni) * 16 + l15;
        short* tile = scw + (mi * TN + ni) * 256;
        short4v pk;
#pragma unroll
        for (int r = 0; r < 4; r++) {
          float v = acc[mi][ni][r];
          if constexpr (EPI == 0) {
            v += bias[col];
            v = v / (1.0f + __expf(-v));            // silu
          } else {
            v *= 0.022097086912079608f;             // 1/sqrt(2048)
            v = fmaxf(v, 0.0f);
            v = v * v;
          }
          short sv = f2bf(v);
          if (!vt) tile[(qd4 + r) * 16 + (l15 ^ (((qd4 + r) & 4) << 1))] = sv;
          else pk[r] = sv;
        }
        if (vt)   // transposed tile[col][row]; rows qd4..qd4+3 contiguous -> b64
          *(short4v*)&tile[l15 * 16 + (qd4 ^ ((l15 & 4) << 1))] = pk;
      }
    __syncthreads();
    int rw = lane & 15, g = (lane >> 4) & 1;
#pragma unroll
    for (int fp = 0; fp < 8; fp++) {
      int id = fp * 2 + (lane >> 5);
      int mi = id >> 2, ni = id & 3;
      const short* tile = scw + id * 256;
      short8 val = *(const short8*)&tile[rw * 16 + ((g ^ ((rw >> 2) & 1)) << 3)];
      if constexpr (EPI == 1) {
        int m = (mf0 + mi) * 16 + rw;
        int c0 = (nf0 + ni) * 16 + g * 8;
        *(short8*)&o0[(long)z * Ppb + pL(m, c0, 64)] = val;
      } else if (!vt) {
        int m = (mf0 + mi) * 16 + rw;
        int c0 = (nf0 + ni) * 16 + g * 8;
        int which = bx / 6;                      // block-uniform
        int d0 = c0 - which * HD;
        int batch = m >> 11, ii = m & (TT - 1);
        if (which == 0)      *(short8*)&o0[(long)m * HD + d0] = val;
        else if (which == 1) *(short8*)&o1[(long)batch * QKpb + pL(ii, d0, 24)] = val;
        else                 *(short8*)&o2[(long)batch * QKpb + pL(ii, d0, 24)] = val;
      } else {
        int d = (nf0 + ni) * 16 + rw - 3 * HD;   // tile row = original col
        int m0 = (mf0 + mi) * 16 + g * 8;        // 8 consecutive output rows
        int batch = m0 >> 11, ii0 = m0 & (TT - 1);
        *(short8*)&o3[(long)batch * QKpb + pL(d, ii0, 64)] = val;
      }
    }
  } else {
    // EPI 2/3: f32 scratch (no early rounding), TM/2 passes of 8 frags (8 KB/wave)
    float* scf = (float*)(smem + w * 8192);
#pragma unroll
    for (int half = 0; half < TM / 2; half++) {
#pragma unroll
      for (int mi2 = 0; mi2 < 2; mi2++)
#pragma unroll
        for (int ni = 0; ni < TN; ni++) {
          float* tile = scf + (mi2 * TN + ni) * 256;
          int mi = half * 2 + mi2;
#pragma unroll
          for (int r = 0; r < 4; r++)
            tile[(qd4 + r) * 16 + (l15 ^ (((qd4 + r) & 4) << 1))] = acc[mi][ni][r];
        }
      __syncthreads();
      int rw = lane & 15, g4 = lane >> 4;
#pragma unroll
      for (int cp = 0; cp < 8; cp++) {
        int mi = half * 2 + (cp >> 2), ni = cp & 3;
        const float* tile = scf + cp * 256;
        floatx4 val = *(const floatx4*)&tile[rw * 16 + ((g4 ^ (((rw >> 2) & 1) << 1)) << 2)];
        int m = (mf0 + mi) * 16 + rw;
        int c0 = (nf0 + ni) * 16 + g4 * 4;
        if constexpr (EPI == 2) {
          long gm = (long)z * TT + m;
          short4v u = *(const short4v*)&umul[gm * HD + c0];
          short4v gv;
#pragma unroll
          for (int j = 0; j < 4; j++) gv[j] = f2bf(val[j] * bf2f(u[j]));
          *(short4v*)&o0[pL((int)gm, c0, 24)] = gv;
        } else {
          floatx4 bv = *(const floatx4*)&bias[c0];
          *(floatx4*)&outf[(long)m * HD + c0] = val + bv;
        }
      }
      __syncthreads();
    }
  }
}

extern "C" void kernel_launch(void* const* d_in, const int* in_sizes, int n_in,
                              void* d_out, int out_size, void* d_ws, size_t ws_size,
                              hipStream_t stream) {
  (void)in_sizes; (void)n_in; (void)out_size; (void)ws_size;
  const float* hid = (const float*)d_in[0];
  const float* lng = (const float*)d_in[1];
  const float* lnb = (const float*)d_in[2];
  const float* Wu  = (const float*)d_in[3];
  const float* bu  = (const float*)d_in[4];
  const float* Wq  = (const float*)d_in[5];
  const float* bq  = (const float*)d_in[6];
  const float* Wk  = (const float*)d_in[7];
  const float* bk  = (const float*)d_in[8];
  const float* Wv  = (const float*)d_in[9];
  const float* bv  = (const float*)d_in[10];
  const float* Wo  = (const float*)d_in[11];
  const float* bo  = (const float*)d_in[12];

  // workspace layout (bytes); packed buffers
  char* ws = (char*)d_ws;
  short* Wb   = (short*)(ws);                 // 5*589824 bf16 = 5,898,240 B (packed)
  float* bcat = (float*)(ws + 5898240);       // 3072 fp32     =    12,288 B
  short* xbf  = (short*)(ws + 5910528);       // x pack, 12,582,912 B
  short* Ub   = (short*)(ws + 18493440);      // U row-major, 12,582,912 B
  short* Qb   = (short*)(ws + 31076352);      // Q pack, 12,582,912 B
  short* Kb   = (short*)(ws + 43659264);      // K pack, 12,582,912 B
  short* Vt   = (short*)(ws + 56242176);      // Vt pack, 12,582,912 B
  short* Pb   = (short*)(ws + 68825088);      // P pack, 33,554,432 B
  short* Gb   = (short*)(ws + 102379520);     // G pack, 12,582,912 B (total ~115 MB)

  // preprocessing: [0,512) LN slabs, [512,752) weight slabs, 752 bias
  pre_kernel<<<753, 256, 0, stream>>>(hid, lng, lnb, xbf,
      Wu, Wq, Wk, Wv, Wo, bu, bq, bk, bv, Wb, bcat);

  // U,Q,K,V = silu(x @ Wcat^T + bcat): block 128x128 (TM=4) @3/CU, GY=64, GX=24
  wgemm<0, 24, 1, 4, 4, 2, 64, 3><<<1536, 256, 0, stream>>>(
      xbf, Wb, 0, 0, Ub, Qb, Kb, Vt, nullptr, bcat, nullptr);

  // P = relu(QK^T/sqrt(T))^2 per batch: 2-phase 128x128 @4/CU, GY=16, GX=16, GZ=4
  wgemm<1, 24, 4, 4, 4, 2, 16, 4><<<1024, 256, 0, stream>>>(
      Qb, Kb, QKpb, QKpb, Pb, nullptr, nullptr, nullptr, nullptr, nullptr, nullptr);

  // G = (P @ V) * U per batch: staged 64x128 (TM=2) @4/CU, GY=32, GX=6, GZ=4 -> 768
  wgemm<2, 64, 4, 2, 4, 2, 32, 4><<<768, 256, 0, stream>>>(
      Pb, Vt, Ppb, QKpb, Gb, nullptr, nullptr, nullptr, nullptr, nullptr, Ub);

  // out = G @ Wo^T + bo: staged 64x128 (TM=2) @4/CU, GY=128, GX=6 -> 768 blocks
  wgemm<3, 24, 1, 2, 4, 2, 128, 4><<<768, 256, 0, stream>>>(
      Gb, Wb + 4 * WElem, 0, 0, nullptr, nullptr, nullptr, nullptr,
      (float*)d_out, bo, nullptr);
}